// Round 8
// baseline (237.185 us; speedup 1.0000x reference)
//
#include <hip/hip_runtime.h>
#include <math.h>

#define Bn 8
#define Cn 64
#define Hn 128
#define Wn 128
#define HWn (Hn * Wn)

// weight fragment regions (shorts)
#define WOM_OFF 0
#define WDC_OFF 18432
#define WC_OFF 55296

typedef __attribute__((ext_vector_type(8))) short short8;
typedef __attribute__((ext_vector_type(4))) float floatx4;

__device__ __forceinline__ float bf2f(short s) {
  return __uint_as_float(((unsigned)(unsigned short)s) << 16);
}
__device__ __forceinline__ short f2bf(float f) {
  unsigned u = __float_as_uint(f);
  u += 0x7fff + ((u >> 16) & 1);  // RNE
  return (short)(u >> 16);
}

// ---------------------------------------------------------------------------
// Prep 1: weights -> bf16 MFMA-A-fragment order (unchanged).
// ---------------------------------------------------------------------------
__global__ __launch_bounds__(256) void k_prep_w(
    const float* __restrict__ w_om, const float* __restrict__ w_dc,
    const float* __restrict__ w_c, short* __restrict__ wt) {
  int idx = blockIdx.x * 256 + threadIdx.x;
  if (idx >= 92160) return;
  float v;
  if (idx < WDC_OFF) {  // om region, MT=2 (M=32)
    int e = idx;
    int elem = e & 7, lane = (e >> 3) & 63, mt = (e >> 9) & 1, t = e >> 10;
    int kk = t % 9, cc = t / 9;
    int row = mt * 16 + (lane & 15);
    int cin = cc * 32 + (lane >> 4) * 8 + elem;
    v = (row < 27) ? w_om[(row * 64 + cin) * 9 + kk] : 0.f;
  } else {  // dc / c regions, MT=4 (M=64)
    int e = (idx < WC_OFF) ? idx - WDC_OFF : idx - WC_OFF;
    const float* src = (idx < WC_OFF) ? w_dc : w_c;
    int elem = e & 7, lane = (e >> 3) & 63, mt = (e >> 9) & 3, t = e >> 11;
    int kk = t % 9, cc = t / 9;
    int row = mt * 16 + (lane & 15);
    int cin = cc * 32 + (lane >> 4) * 8 + elem;
    v = src[(row * 64 + cin) * 9 + kk];
  }
  wt[idx] = f2bf(v);
}

// ---------------------------------------------------------------------------
// Prep 2: x fp32 NCHW -> bf16 channels-last xT[b][h][w][64] (unchanged).
// ---------------------------------------------------------------------------
__global__ __launch_bounds__(256) void k_prep_x(const float* __restrict__ x,
                                                short* __restrict__ xT) {
  __shared__ float tile[64][129];
  const int bid = blockIdx.x;
  const int b = bid & 7, h = bid >> 3;
  const int tid = threadIdx.x;
  const float* xb = x + (size_t)b * 64 * HWn + h * Wn;
  for (int i = tid; i < 8192; i += 256) {
    int c = i >> 7, w = i & 127;
    tile[c][w] = xb[c * HWn + w];
  }
  __syncthreads();
  short* dst = xT + ((size_t)(b * Hn + h) * Wn) * 64;
  for (int i = tid; i < 2048; i += 256) {
    int w = i >> 4, c4 = (i & 15) * 4;
    short4 o;
    o.x = f2bf(tile[c4 + 0][w]);
    o.y = f2bf(tile[c4 + 1][w]);
    o.z = f2bf(tile[c4 + 2][w]);
    o.w = f2bf(tile[c4 + 3][w]);
    *(short4*)(dst + (size_t)w * 64 + c4) = o;
  }
}

// ---------------------------------------------------------------------------
// R8 k_omdef: gathers OFF the TA. Diagnosis: ~160K/240K cycles per SIMD idle
// with 8 resident waves — the shared per-CU vector-memory address pipe is
// saturated by 64-lane divergent gathers (invariant to occupancy/barriers/
// fission across R0-R7). Fix: stage 5 clamped rows (h-2..h+2, 80KB, XOR-
// swizzled) once per block; ALL bilinear corners become ds_read_b128 when
// offy in [-1,1) (per-tap wave-uniform __all gate; else exact R7 global
// fallback — offsets here are ~N(0,0.06) so LDS path ~always). Params inline
// wave-local (R7 piece). A direct-global (L2-hot, coalesced). One barrier.
// LDS 94.2KB -> 1 block/CU (8 waves) — intentional: if TA is the wall, LDS
// bandwidth replaces it and 8 waves suffice.
// ---------------------------------------------------------------------------
__global__ __launch_bounds__(512, 2) void k_omdef(
    const short* __restrict__ xT, const short* __restrict__ wt,
    const float* __restrict__ b_om, const float* __restrict__ b_dc,
    short* __restrict__ actT) {
  __shared__ __attribute__((aligned(16))) short rows[40960];  // 80KB: 5 rows
  __shared__ float som[27 * 132];                             // 14.0KB

  const int bid = blockIdx.x;
  const int b = bid & 7;
  const int h = bid >> 3;
  const int tid = threadIdx.x;
  const int wave = tid >> 6, lane = tid & 63, quad = lane >> 4, lr = lane & 15;
  const short* xb = xT + (size_t)b * HWn * 64;
  const int pxl = wave * 16 + lr;  // block-local pixel = global x (full row)

  floatx4 zf = {0.f, 0.f, 0.f, 0.f};
  const short8 zz = (short8){0, 0, 0, 0, 0, 0, 0, 0};
  short8* rows8 = (short8*)rows;

  // ---- stage 5 clamped rows h-2..h+2, XOR-swizzled 16B slots ----
  {
    const short8* xr8 = (const short8*)xb;
    for (int i = tid; i < 5120; i += 512) {
      int rr = i >> 10, c = i & 1023;
      int px = c >> 3, sl = c & 7;
      int gy = min(max(h - 2 + rr, 0), Hn - 1);
      short8 v = xr8[(size_t)(gy * Wn + px) * 8 + sl];
      rows8[(rr << 10) + (px << 3) + (sl ^ (px & 7))] = v;
    }
  }
  __syncthreads();

  // ================= phase 1: conv_om (M=32), B from rows ==================
  floatx4 aco[2] = {zf, zf};
#pragma unroll 3
  for (int kk = 0; kk < 9; ++kk) {
    int ky = kk / 3, kx = kk - ky * 3;
    int gy = h + ky - 1, gx = pxl + kx - 1;
    bool ok = ((unsigned)gy < (unsigned)Hn) && ((unsigned)gx < (unsigned)Wn);
    int gxc = min(max(gx, 0), Wn - 1);
#pragma unroll
    for (int cc = 0; cc < 2; ++cc) {
      // staged row (ky+1) holds clamp(h-2+(ky+1)) == clamp(h+ky-1)
      short8 bf =
          rows8[((ky + 1) << 10) + (gxc << 3) + ((cc * 4 + quad) ^ (gxc & 7))];
      if (!ok) bf = zz;
      short8 a0 = *(const short8*)(wt + WOM_OFF +
                                   ((cc * 9 + kk) * 2 + 0) * 512 + lane * 8);
      short8 a1 = *(const short8*)(wt + WOM_OFF +
                                   ((cc * 9 + kk) * 2 + 1) * 512 + lane * 8);
      aco[0] = __builtin_amdgcn_mfma_f32_16x16x32_bf16(a0, bf, aco[0], 0, 0, 0);
      aco[1] = __builtin_amdgcn_mfma_f32_16x16x32_bf16(a1, bf, aco[1], 0, 0, 0);
    }
  }
  // om epilogue -> som (this wave's 16 columns only; som is wave-local)
#pragma unroll
  for (int mt = 0; mt < 2; ++mt) {
#pragma unroll
    for (int rr = 0; rr < 4; ++rr) {
      int co = mt * 16 + quad * 4 + rr;
      if (co < 27) {
        float v = aco[mt][rr] + b_om[co];
        if (co >= 18) v = 2.f / (1.f + expf(-v));
        som[co * 132 + pxl] = v;
      }
    }
  }
  asm volatile("s_waitcnt lgkmcnt(0)" ::: "memory");

  // ====== phase 2: deformable conv (M=64), gathers from LDS ================
  floatx4 acc[4] = {zf, zf, zf, zf};
  const short* wdc = wt + WDC_OFF;
  const int cq = quad * 8;
#pragma unroll 3
  for (int kk = 0; kk < 9; ++kk) {
    float offy = som[(2 * kk) * 132 + pxl];
    float offx = som[(2 * kk + 1) * 132 + pxl];
    float m = som[(18 + kk) * 132 + pxl];
    float py = (float)(h - 1 + (kk / 3)) + offy;
    float px_ = (float)(pxl - 1 + (kk % 3)) + offx;
    float fy = floorf(py), fx = floorf(px_);
    float ly = py - fy, lx = px_ - fx;
    int iy0 = (int)fy, ix0 = (int)fx;
    int iy1 = iy0 + 1, ix1 = ix0 + 1;
    bool vy0 = ((unsigned)iy0 < (unsigned)Hn);
    bool vy1 = ((unsigned)iy1 < (unsigned)Hn);
    bool vx0 = ((unsigned)ix0 < (unsigned)Wn);
    bool vx1 = ((unsigned)ix1 < (unsigned)Wn);
    int cy0 = min(max(iy0, 0), Hn - 1);
    int cy1 = min(max(iy1, 0), Hn - 1);
    int cx0 = min(max(ix0, 0), Wn - 1);
    int cx1 = min(max(ix1, 0), Wn - 1);
    float u0 = (vy0 && vx0) ? (1.f - ly) * (1.f - lx) * m : 0.f;
    float u1 = (vy0 && vx1) ? (1.f - ly) * lx * m : 0.f;
    float u2 = (vy1 && vx0) ? ly * (1.f - lx) * m : 0.f;
    float u3 = (vy1 && vx1) ? ly * lx * m : 0.f;

    short8 q0, q1, q2, q3, r0, r1, r2, r3;
    bool inb = (offy >= -1.0f) && (offy < 1.0f);
    if (__all((int)inb)) {
      // LDS path: staged row index j = cy - (h-2), in [0,4] by the gate
      int j0 = cy0 - h + 2, j1 = cy1 - h + 2;
      int s0q = (cq >> 3), s1q = 4 + (cq >> 3);  // cc0 slot, cc1 slot (pre-XOR)
      q0 = rows8[(j0 << 10) + (cx0 << 3) + (s0q ^ (cx0 & 7))];
      q1 = rows8[(j0 << 10) + (cx1 << 3) + (s0q ^ (cx1 & 7))];
      q2 = rows8[(j1 << 10) + (cx0 << 3) + (s0q ^ (cx0 & 7))];
      q3 = rows8[(j1 << 10) + (cx1 << 3) + (s0q ^ (cx1 & 7))];
      r0 = rows8[(j0 << 10) + (cx0 << 3) + (s1q ^ (cx0 & 7))];
      r1 = rows8[(j0 << 10) + (cx1 << 3) + (s1q ^ (cx1 & 7))];
      r2 = rows8[(j1 << 10) + (cx0 << 3) + (s1q ^ (cx0 & 7))];
      r3 = rows8[(j1 << 10) + (cx1 << 3) + (s1q ^ (cx1 & 7))];
    } else {
      // global fallback (exact R7 path) — essentially never taken
      unsigned d0 = (unsigned)(cy0 * Wn + cx0), d1 = (unsigned)(cy0 * Wn + cx1);
      unsigned d2 = (unsigned)(cy1 * Wn + cx0), d3 = (unsigned)(cy1 * Wn + cx1);
      q0 = *(const short8*)(xb + (size_t)d0 * 64 + cq);
      q1 = *(const short8*)(xb + (size_t)d1 * 64 + cq);
      q2 = *(const short8*)(xb + (size_t)d2 * 64 + cq);
      q3 = *(const short8*)(xb + (size_t)d3 * 64 + cq);
      r0 = *(const short8*)(xb + (size_t)d0 * 64 + 32 + cq);
      r1 = *(const short8*)(xb + (size_t)d1 * 64 + 32 + cq);
      r2 = *(const short8*)(xb + (size_t)d2 * 64 + 32 + cq);
      r3 = *(const short8*)(xb + (size_t)d3 * 64 + 32 + cq);
    }

    short8 bf0, bf1;
#pragma unroll
    for (int e = 0; e < 8; ++e) {
      float f = u0 * bf2f(q0[e]) + u1 * bf2f(q1[e]) + u2 * bf2f(q2[e]) +
                u3 * bf2f(q3[e]);
      bf0[e] = f2bf(f);
    }
#pragma unroll
    for (int e = 0; e < 8; ++e) {
      float f = u0 * bf2f(r0[e]) + u1 * bf2f(r1[e]) + u2 * bf2f(r2[e]) +
                u3 * bf2f(r3[e]);
      bf1[e] = f2bf(f);
    }

#pragma unroll
    for (int mt = 0; mt < 4; ++mt) {
      short8 a0 = *(const short8*)(wdc + ((0 * 9 + kk) * 4 + mt) * 512 +
                                   lane * 8);
      acc[mt] = __builtin_amdgcn_mfma_f32_16x16x32_bf16(a0, bf0, acc[mt], 0, 0, 0);
    }
#pragma unroll
    for (int mt = 0; mt < 4; ++mt) {
      short8 a1 = *(const short8*)(wdc + ((1 * 9 + kk) * 4 + mt) * 512 +
                                   lane * 8);
      acc[mt] = __builtin_amdgcn_mfma_f32_16x16x32_bf16(a1, bf1, acc[mt], 0, 0, 0);
    }
  }

  // epilogue: bias + leaky ReLU -> actT[b][h][w][64]
  short* ab = actT + ((size_t)(b * Hn + h) * Wn) * 64;
#pragma unroll
  for (int mt = 0; mt < 4; ++mt) {
    int c0 = mt * 16 + quad * 4;
    short4 o;
    float v;
    v = acc[mt][0] + b_dc[c0 + 0]; o.x = f2bf(v > 0.f ? v : 0.2f * v);
    v = acc[mt][1] + b_dc[c0 + 1]; o.y = f2bf(v > 0.f ? v : 0.2f * v);
    v = acc[mt][2] + b_dc[c0 + 2]; o.z = f2bf(v > 0.f ? v : 0.2f * v);
    v = acc[mt][3] + b_dc[c0 + 3]; o.w = f2bf(v > 0.f ? v : 0.2f * v);
    *(short4*)(ab + (size_t)pxl * 64 + c0) = o;
  }
}

// ---------------------------------------------------------------------------
// conv_out: EXACT R6 version (control). LDS row-cache of 3 actT rows
// (XOR-swizzled); B = conflict-free ds_read_b128; A = direct-global.
// ---------------------------------------------------------------------------
__global__ __launch_bounds__(512, 4) void k_conv_out(
    const short* __restrict__ actT, const short* __restrict__ wt,
    const float* __restrict__ b_c, const float* __restrict__ x,
    float* __restrict__ out) {
  __shared__ __attribute__((aligned(16))) short rows[24576];  // 48KB

  const int bid = blockIdx.x;
  const int b = bid & 7;
  const int h = bid >> 3;
  const int tid = threadIdx.x;
  const int wave = tid >> 6, lane = tid & 63, quad = lane >> 4, lr = lane & 15;
  const short* ab = actT + (size_t)b * HWn * 64;
  const int pxl = wave * 16 + lr;

  floatx4 zf = {0.f, 0.f, 0.f, 0.f};
  const short8 zz = (short8){0, 0, 0, 0, 0, 0, 0, 0};
  floatx4 acc[4] = {zf, zf, zf, zf};
  short8* rows8 = (short8*)rows;

  // ---- stage 3 clamped act rows, XOR-swizzled ----
  {
    const short8* ar8 = (const short8*)ab;
    for (int i = tid; i < 3072; i += 512) {
      int rr = i >> 10, c = i & 1023;
      int px = c >> 3, sl = c & 7;
      int gy = min(max(h - 1 + rr, 0), Hn - 1);
      short8 v = ar8[(size_t)(gy * Wn + px) * 8 + sl];
      rows8[(rr << 10) + (px << 3) + (sl ^ (px & 7))] = v;
    }
  }
  __syncthreads();

#pragma unroll
  for (int cc = 0; cc < 2; ++cc) {
#pragma unroll
    for (int kk = 0; kk < 9; ++kk) {
      int ky = kk / 3, kx = kk - ky * 3;
      int gy = h + ky - 1, gxx = pxl + kx - 1;
      bool ok = ((unsigned)gy < (unsigned)Hn) && ((unsigned)gxx < (unsigned)Wn);
      int gxc = min(max(gxx, 0), Wn - 1);
      short8 bf = rows8[(ky << 10) + (gxc << 3) + ((cc * 4 + quad) ^ (gxc & 7))];
      if (!ok) bf = zz;
#pragma unroll
      for (int mt = 0; mt < 4; ++mt) {
        short8 am = *(const short8*)(wt + WC_OFF + cc * 18432 +
                                     (kk * 4 + mt) * 512 + lane * 8);
        acc[mt] = __builtin_amdgcn_mfma_f32_16x16x32_bf16(am, bf, acc[mt], 0, 0, 0);
      }
    }
  }
  __syncthreads();  // all rows reads done; reuse as fp32 tile

  // transpose acc -> ot[cout][px] (stride 132; 64*132*4B = 33.8KB <= 48KB)
  float* ot = (float*)rows;
#pragma unroll
  for (int mt = 0; mt < 4; ++mt) {
#pragma unroll
    for (int rr = 0; rr < 4; ++rr) {
      ot[(mt * 16 + quad * 4 + rr) * 132 + pxl] = acc[mt][rr];
    }
  }
  __syncthreads();

  // coalesced epilogue: thread = (cout row, 16-px segment); 64 x 8 segs
  const int row = tid >> 3, seg = tid & 7;
  const float bias = b_c[row];
  const size_t gbase = ((size_t)(b * 64 + row) * Hn + h) * Wn + seg * 16;
  const float* xr = x + gbase;
  float* op = out + gbase;
#pragma unroll
  for (int j = 0; j < 4; ++j) {
    floatx4 t = *(const floatx4*)&ot[row * 132 + seg * 16 + j * 4];
    floatx4 xv = *(const floatx4*)&xr[j * 4];
    t = t + xv;
    t[0] += bias; t[1] += bias; t[2] += bias; t[3] += bias;
    *(floatx4*)&op[j * 4] = t;
  }
}

// ---------------------------------------------------------------------------
extern "C" void kernel_launch(void* const* d_in, const int* in_sizes, int n_in,
                              void* d_out, int out_size, void* d_ws,
                              size_t ws_size, hipStream_t stream) {
  const float* x = (const float*)d_in[0];
  const float* w_om = (const float*)d_in[1];
  const float* b_om = (const float*)d_in[2];
  const float* w_dc = (const float*)d_in[3];
  const float* b_dc = (const float*)d_in[4];
  const float* w_c = (const float*)d_in[5];
  const float* b_c = (const float*)d_in[6];
  float* out = (float*)d_out;

  // ws: xT bf16 (16.8 MB) | actT bf16 (16.8 MB) | weight frags (184 KB)
  short* xT = (short*)d_ws;
  short* actT = xT + (size_t)Bn * HWn * 64;
  short* wt = actT + (size_t)Bn * HWn * 64;

  k_prep_w<<<dim3(360), 256, 0, stream>>>(w_om, w_dc, w_c, wt);
  k_prep_x<<<dim3(1024), 256, 0, stream>>>(x, xT);
  k_omdef<<<dim3(1024), 512, 0, stream>>>(xT, wt, b_om, b_dc, actT);
  k_conv_out<<<dim3(1024), 512, 0, stream>>>(actT, wt, b_c, x, out);
}

// Round 9
// 216.740 us; speedup vs baseline: 1.0943x; 1.0943x over previous
//
#include <hip/hip_runtime.h>
#include <math.h>

#define Bn 8
#define Cn 64
#define Hn 128
#define Wn 128
#define HWn (Hn * Wn)

// weight fragment regions (shorts)
#define WOM_OFF 0
#define WDC_OFF 18432
#define WC_OFF 55296

typedef __attribute__((ext_vector_type(8))) short short8;
typedef __attribute__((ext_vector_type(4))) float floatx4;

__device__ __forceinline__ float bf2f(short s) {
  return __uint_as_float(((unsigned)(unsigned short)s) << 16);
}
__device__ __forceinline__ short f2bf(float f) {
  unsigned u = __float_as_uint(f);
  u += 0x7fff + ((u >> 16) & 1);  // RNE
  return (short)(u >> 16);
}

// ---------------------------------------------------------------------------
// Prep 1: weights -> bf16 MFMA-A-fragment order (unchanged).
// ---------------------------------------------------------------------------
__global__ __launch_bounds__(256) void k_prep_w(
    const float* __restrict__ w_om, const float* __restrict__ w_dc,
    const float* __restrict__ w_c, short* __restrict__ wt) {
  int idx = blockIdx.x * 256 + threadIdx.x;
  if (idx >= 92160) return;
  float v;
  if (idx < WDC_OFF) {  // om region, MT=2 (M=32)
    int e = idx;
    int elem = e & 7, lane = (e >> 3) & 63, mt = (e >> 9) & 1, t = e >> 10;
    int kk = t % 9, cc = t / 9;
    int row = mt * 16 + (lane & 15);
    int cin = cc * 32 + (lane >> 4) * 8 + elem;
    v = (row < 27) ? w_om[(row * 64 + cin) * 9 + kk] : 0.f;
  } else {  // dc / c regions, MT=4 (M=64)
    int e = (idx < WC_OFF) ? idx - WDC_OFF : idx - WC_OFF;
    const float* src = (idx < WC_OFF) ? w_dc : w_c;
    int elem = e & 7, lane = (e >> 3) & 63, mt = (e >> 9) & 3, t = e >> 11;
    int kk = t % 9, cc = t / 9;
    int row = mt * 16 + (lane & 15);
    int cin = cc * 32 + (lane >> 4) * 8 + elem;
    v = src[(row * 64 + cin) * 9 + kk];
  }
  wt[idx] = f2bf(v);
}

// ---------------------------------------------------------------------------
// Prep 2: x fp32 NCHW -> bf16 channels-last xT[b][h][w][64] (unchanged).
// ---------------------------------------------------------------------------
__global__ __launch_bounds__(256) void k_prep_x(const float* __restrict__ x,
                                                short* __restrict__ xT) {
  __shared__ float tile[64][129];
  const int bid = blockIdx.x;
  const int b = bid & 7, h = bid >> 3;
  const int tid = threadIdx.x;
  const float* xb = x + (size_t)b * 64 * HWn + h * Wn;
  for (int i = tid; i < 8192; i += 256) {
    int c = i >> 7, w = i & 127;
    tile[c][w] = xb[c * HWn + w];
  }
  __syncthreads();
  short* dst = xT + ((size_t)(b * Hn + h) * Wn) * 64;
  for (int i = tid; i < 2048; i += 256) {
    int w = i >> 4, c4 = (i & 15) * 4;
    short4 o;
    o.x = f2bf(tile[c4 + 0][w]);
    o.y = f2bf(tile[c4 + 1][w]);
    o.z = f2bf(tile[c4 + 2][w]);
    o.w = f2bf(tile[c4 + 3][w]);
    *(short4*)(dst + (size_t)w * 64 + c4) = o;
  }
}

// ---------------------------------------------------------------------------
// R9 k_omdef: 2 output rows per block, grid 512 = 2 blocks/CU = ONE round.
// Proven levers only: per-block amortization (R4, -14%), A staged in LDS
// (R7/R8 showed removing it costs +15us), A-frags read ONCE per (cc,kk) and
// reused for both rows (halves A-LDS traffic), inline wave-local params
// (R7-proven correct; kills sbw buffer + barrier). LDS 36.9(lw)+28.5(som)
// = 65.4KB -> 2 blocks/CU = 16 waves.
// ---------------------------------------------------------------------------
__global__ __launch_bounds__(512, 4) void k_omdef(
    const short* __restrict__ xT, const short* __restrict__ wt,
    const float* __restrict__ b_om, const float* __restrict__ b_dc,
    short* __restrict__ actT) {
  __shared__ __attribute__((aligned(16))) short lw[18432];  // 36.9KB A-stage
  __shared__ float som[2][27 * 132];                        // 28.5KB

  const int bid = blockIdx.x;
  const int b = bid & 7;
  const int h0 = (bid >> 3) * 2;  // first of the two output rows
  const int tid = threadIdx.x;
  const int wave = tid >> 6, lane = tid & 63, quad = lane >> 4, lr = lane & 15;
  const short* xb = xT + (size_t)b * HWn * 64;
  const int pxl = wave * 16 + lr;

  floatx4 zf = {0.f, 0.f, 0.f, 0.f};
  const short8 zz = (short8){0, 0, 0, 0, 0, 0, 0, 0};

  // ---- stage om A-fragments (both cc halves, 36.9KB) ----
  {
    const short8* src = (const short8*)(wt + WOM_OFF);
    short8* dst = (short8*)lw;
    for (int i = tid; i < 2304; i += 512) dst[i] = src[i];
  }
  __syncthreads();

  // ========== phase 1: conv_om (M=32), A shared across both rows ==========
  floatx4 aco[2][2] = {{zf, zf}, {zf, zf}};
#pragma unroll 3
  for (int kk = 0; kk < 9; ++kk) {
    int ky = kk / 3, kx = kk - ky * 3;
    int gx = pxl + kx - 1;
    bool okx = ((unsigned)gx < (unsigned)Wn);
    int gxc = min(max(gx, 0), Wn - 1);
#pragma unroll
    for (int cc = 0; cc < 2; ++cc) {
      short8 a0 = *(const short8*)&lw[((cc * 9 + kk) * 2 + 0) * 512 + lane * 8];
      short8 a1 = *(const short8*)&lw[((cc * 9 + kk) * 2 + 1) * 512 + lane * 8];
#pragma unroll
      for (int r = 0; r < 2; ++r) {
        int gy = h0 + r + ky - 1;
        bool ok = okx && ((unsigned)gy < (unsigned)Hn);
        int gyc = min(max(gy, 0), Hn - 1);
        short8 bf = *(const short8*)(xb + (size_t)(gyc * Wn + gxc) * 64 +
                                     cc * 32 + quad * 8);
        if (!ok) bf = zz;
        aco[r][0] = __builtin_amdgcn_mfma_f32_16x16x32_bf16(a0, bf, aco[r][0], 0, 0, 0);
        aco[r][1] = __builtin_amdgcn_mfma_f32_16x16x32_bf16(a1, bf, aco[r][1], 0, 0, 0);
      }
    }
  }
  // om epilogue -> som (wave-local columns)
#pragma unroll
  for (int r = 0; r < 2; ++r) {
#pragma unroll
    for (int mt = 0; mt < 2; ++mt) {
#pragma unroll
      for (int rr = 0; rr < 4; ++rr) {
        int co = mt * 16 + quad * 4 + rr;
        if (co < 27) {
          float v = aco[r][mt][rr] + b_om[co];
          if (co >= 18) v = 2.f / (1.f + expf(-v));
          som[r][co * 132 + pxl] = v;
        }
      }
    }
  }
  asm volatile("s_waitcnt lgkmcnt(0)" ::: "memory");

  // ========== phase 2: deformable conv (M=64), A shared across rows =======
  floatx4 acc[2][4] = {{zf, zf, zf, zf}, {zf, zf, zf, zf}};
  for (int cc = 0; cc < 2; ++cc) {
    // stage this cc's dc A-half (36.9KB)
    __syncthreads();  // previous lw reads done
    {
      const short8* src = (const short8*)(wt + WDC_OFF + cc * 18432);
      short8* dst = (short8*)lw;
      for (int i = tid; i < 2304; i += 512) dst[i] = src[i];
    }
    __syncthreads();
    const int co = cc * 32 + quad * 8;
#pragma unroll 3
    for (int kk = 0; kk < 9; ++kk) {
      short8 am0 = *(const short8*)&lw[(kk * 4 + 0) * 512 + lane * 8];
      short8 am1 = *(const short8*)&lw[(kk * 4 + 1) * 512 + lane * 8];
      short8 am2 = *(const short8*)&lw[(kk * 4 + 2) * 512 + lane * 8];
      short8 am3 = *(const short8*)&lw[(kk * 4 + 3) * 512 + lane * 8];
#pragma unroll
      for (int r = 0; r < 2; ++r) {
        // inline bilinear params (wave-local som)
        float offy = som[r][(2 * kk) * 132 + pxl];
        float offx = som[r][(2 * kk + 1) * 132 + pxl];
        float m = som[r][(18 + kk) * 132 + pxl];
        float py = (float)(h0 + r - 1 + (kk / 3)) + offy;
        float px_ = (float)(pxl - 1 + (kk % 3)) + offx;
        float fy = floorf(py), fx = floorf(px_);
        float ly = py - fy, lx = px_ - fx;
        int iy0 = (int)fy, ix0 = (int)fx;
        int iy1 = iy0 + 1, ix1 = ix0 + 1;
        bool vy0 = ((unsigned)iy0 < (unsigned)Hn);
        bool vy1 = ((unsigned)iy1 < (unsigned)Hn);
        bool vx0 = ((unsigned)ix0 < (unsigned)Wn);
        bool vx1 = ((unsigned)ix1 < (unsigned)Wn);
        unsigned cy0 = (unsigned)min(max(iy0, 0), Hn - 1);
        unsigned cy1 = (unsigned)min(max(iy1, 0), Hn - 1);
        unsigned cx0 = (unsigned)min(max(ix0, 0), Wn - 1);
        unsigned cx1 = (unsigned)min(max(ix1, 0), Wn - 1);
        unsigned d0 = cy0 * Wn + cx0, d1 = cy0 * Wn + cx1;
        unsigned d2 = cy1 * Wn + cx0, d3 = cy1 * Wn + cx1;
        float u0 = (vy0 && vx0) ? (1.f - ly) * (1.f - lx) * m : 0.f;
        float u1 = (vy0 && vx1) ? (1.f - ly) * lx * m : 0.f;
        float u2 = (vy1 && vx0) ? ly * (1.f - lx) * m : 0.f;
        float u3 = (vy1 && vx1) ? ly * lx * m : 0.f;

        short8 q0 = *(const short8*)(xb + (size_t)d0 * 64 + co);
        short8 q1 = *(const short8*)(xb + (size_t)d1 * 64 + co);
        short8 q2 = *(const short8*)(xb + (size_t)d2 * 64 + co);
        short8 q3 = *(const short8*)(xb + (size_t)d3 * 64 + co);

        short8 bf;
#pragma unroll
        for (int e = 0; e < 8; ++e) {
          float f = u0 * bf2f(q0[e]) + u1 * bf2f(q1[e]) + u2 * bf2f(q2[e]) +
                    u3 * bf2f(q3[e]);
          bf[e] = f2bf(f);
        }
        acc[r][0] = __builtin_amdgcn_mfma_f32_16x16x32_bf16(am0, bf, acc[r][0], 0, 0, 0);
        acc[r][1] = __builtin_amdgcn_mfma_f32_16x16x32_bf16(am1, bf, acc[r][1], 0, 0, 0);
        acc[r][2] = __builtin_amdgcn_mfma_f32_16x16x32_bf16(am2, bf, acc[r][2], 0, 0, 0);
        acc[r][3] = __builtin_amdgcn_mfma_f32_16x16x32_bf16(am3, bf, acc[r][3], 0, 0, 0);
      }
    }
  }

  // epilogue: bias + leaky ReLU -> actT, both rows
#pragma unroll
  for (int r = 0; r < 2; ++r) {
    short* ab = actT + ((size_t)(b * Hn + h0 + r) * Wn) * 64;
#pragma unroll
    for (int mt = 0; mt < 4; ++mt) {
      int c0 = mt * 16 + quad * 4;
      short4 o;
      float v;
      v = acc[r][mt][0] + b_dc[c0 + 0]; o.x = f2bf(v > 0.f ? v : 0.2f * v);
      v = acc[r][mt][1] + b_dc[c0 + 1]; o.y = f2bf(v > 0.f ? v : 0.2f * v);
      v = acc[r][mt][2] + b_dc[c0 + 2]; o.z = f2bf(v > 0.f ? v : 0.2f * v);
      v = acc[r][mt][3] + b_dc[c0 + 3]; o.w = f2bf(v > 0.f ? v : 0.2f * v);
      *(short4*)(ab + (size_t)pxl * 64 + c0) = o;
    }
  }
}

// ---------------------------------------------------------------------------
// R9 k_conv_out: 2 rows per block, grid 512 = one round. A staged per cc in
// LDS, read once per (cc,kk) and shared by both rows; B = direct shifted
// global reads (proven). Epilogue per row via LDS fp32 transpose.
// ---------------------------------------------------------------------------
__global__ __launch_bounds__(512, 4) void k_conv_out(
    const short* __restrict__ actT, const short* __restrict__ wt,
    const float* __restrict__ b_c, const float* __restrict__ x,
    float* __restrict__ out) {
  __shared__ __attribute__((aligned(16))) short lw[18432];  // 36.9KB

  const int bid = blockIdx.x;
  const int b = bid & 7;
  const int h0 = (bid >> 3) * 2;
  const int tid = threadIdx.x;
  const int wave = tid >> 6, lane = tid & 63, quad = lane >> 4, lr = lane & 15;
  const short* ab = actT + (size_t)b * HWn * 64;
  const int pxl = wave * 16 + lr;

  floatx4 zf = {0.f, 0.f, 0.f, 0.f};
  const short8 zz = (short8){0, 0, 0, 0, 0, 0, 0, 0};
  floatx4 acc[2][4] = {{zf, zf, zf, zf}, {zf, zf, zf, zf}};

  for (int cc = 0; cc < 2; ++cc) {
    if (cc) __syncthreads();  // previous A-reads done
    {
      const short8* src = (const short8*)(wt + WC_OFF + cc * 18432);
      short8* dst = (short8*)lw;
      for (int i = tid; i < 2304; i += 512) dst[i] = src[i];
    }
    __syncthreads();
    const int co = cc * 32 + quad * 8;
#pragma unroll 3
    for (int kk = 0; kk < 9; ++kk) {
      int ky = kk / 3, kx = kk - ky * 3;
      int gx = pxl + kx - 1;
      bool okx = ((unsigned)gx < (unsigned)Wn);
      int gxc = min(max(gx, 0), Wn - 1);
      short8 am0 = *(const short8*)&lw[(kk * 4 + 0) * 512 + lane * 8];
      short8 am1 = *(const short8*)&lw[(kk * 4 + 1) * 512 + lane * 8];
      short8 am2 = *(const short8*)&lw[(kk * 4 + 2) * 512 + lane * 8];
      short8 am3 = *(const short8*)&lw[(kk * 4 + 3) * 512 + lane * 8];
#pragma unroll
      for (int r = 0; r < 2; ++r) {
        int gy = h0 + r + ky - 1;
        bool ok = okx && ((unsigned)gy < (unsigned)Hn);
        int gyc = min(max(gy, 0), Hn - 1);
        short8 bf = *(const short8*)(ab + (size_t)(gyc * Wn + gxc) * 64 + co);
        if (!ok) bf = zz;
        acc[r][0] = __builtin_amdgcn_mfma_f32_16x16x32_bf16(am0, bf, acc[r][0], 0, 0, 0);
        acc[r][1] = __builtin_amdgcn_mfma_f32_16x16x32_bf16(am1, bf, acc[r][1], 0, 0, 0);
        acc[r][2] = __builtin_amdgcn_mfma_f32_16x16x32_bf16(am2, bf, acc[r][2], 0, 0, 0);
        acc[r][3] = __builtin_amdgcn_mfma_f32_16x16x32_bf16(am3, bf, acc[r][3], 0, 0, 0);
      }
    }
  }
  __syncthreads();  // all A-reads done; reuse lw as fp32 tile

  // per-row epilogue: transpose -> coalesced float4 stores + residual
  float* ot = (float*)lw;
#pragma unroll
  for (int r = 0; r < 2; ++r) {
    if (r) __syncthreads();  // previous row's reads done
#pragma unroll
    for (int mt = 0; mt < 4; ++mt) {
#pragma unroll
      for (int rr = 0; rr < 4; ++rr) {
        ot[(mt * 16 + quad * 4 + rr) * 132 + pxl] = acc[r][mt][rr];
      }
    }
    __syncthreads();
    const int row = tid >> 3, seg = tid & 7;
    const float bias = b_c[row];
    const size_t gbase =
        ((size_t)(b * 64 + row) * Hn + h0 + r) * Wn + seg * 16;
    const float* xr = x + gbase;
    float* op = out + gbase;
#pragma unroll
    for (int j = 0; j < 4; ++j) {
      floatx4 t = *(const floatx4*)&ot[row * 132 + seg * 16 + j * 4];
      floatx4 xv = *(const floatx4*)&xr[j * 4];
      t = t + xv;
      t[0] += bias; t[1] += bias; t[2] += bias; t[3] += bias;
      *(floatx4*)&op[j * 4] = t;
    }
  }
}

// ---------------------------------------------------------------------------
extern "C" void kernel_launch(void* const* d_in, const int* in_sizes, int n_in,
                              void* d_out, int out_size, void* d_ws,
                              size_t ws_size, hipStream_t stream) {
  const float* x = (const float*)d_in[0];
  const float* w_om = (const float*)d_in[1];
  const float* b_om = (const float*)d_in[2];
  const float* w_dc = (const float*)d_in[3];
  const float* b_dc = (const float*)d_in[4];
  const float* w_c = (const float*)d_in[5];
  const float* b_c = (const float*)d_in[6];
  float* out = (float*)d_out;

  // ws: xT bf16 (16.8 MB) | actT bf16 (16.8 MB) | weight frags (184 KB)
  short* xT = (short*)d_ws;
  short* actT = xT + (size_t)Bn * HWn * 64;
  short* wt = actT + (size_t)Bn * HWn * 64;

  k_prep_w<<<dim3(360), 256, 0, stream>>>(w_om, w_dc, w_c, wt);
  k_prep_x<<<dim3(1024), 256, 0, stream>>>(x, xT);
  k_omdef<<<dim3(512), 512, 0, stream>>>(xT, wt, b_om, b_dc, actT);
  k_conv_out<<<dim3(512), 512, 0, stream>>>(actT, wt, b_c, x, out);
}